// Round 1
// baseline (249.473 us; speedup 1.0000x reference)
//
#include <hip/hip_runtime.h>

#define N_FLOWS 20
#define DIM 4
#define ITEMS 8
#define BLOCK 256

// Chain of 20 pyro-style radial flows on dim-4 fp32 vectors.
//   alpha = softplus(a'), beta = -alpha + softplus(b')
//   y = x + beta * (x - x0) / (alpha + ||x - x0||)
// Memory-bound: 128 MB in + 128 MB out -> ~42 us floor at 6.3 TB/s.
// HW-approx sqrt/rcp (v_sqrt_f32 / v_rcp_f32) keep VALU below the memory
// floor; threshold (1.33e-1) is orders of magnitude above their error.
__global__ __launch_bounds__(BLOCK) void radial_flow_kernel(
    const float* __restrict__ X,
    const float* __restrict__ x0s,          // [N_FLOWS, 4]
    const float* __restrict__ alpha_primes, // [N_FLOWS]
    const float* __restrict__ beta_primes,  // [N_FLOWS]
    float* __restrict__ out,
    int batch)
{
    const float4* __restrict__ Xv = (const float4*)X;
    const float4* __restrict__ x0v = (const float4*)x0s;
    float4* __restrict__ Ov = (float4*)out;

    const long base = (long)blockIdx.x * (BLOCK * ITEMS) + threadIdx.x;

    float4 x[ITEMS];
    bool ok[ITEMS];
#pragma unroll
    for (int i = 0; i < ITEMS; ++i) {
        long idx = base + (long)i * BLOCK;
        ok[i] = idx < batch;
        if (ok[i]) x[i] = Xv[idx];
    }

    // Flows outer (params have short live ranges), items inner (8-way ILP
    // so the sqrt->rcp dependent chain pipelines).
#pragma unroll
    for (int f = 0; f < N_FLOWS; ++f) {
        // softplus on wave-uniform scalars: 2 transcendentals per flow per
        // thread, amortized over ITEMS samples.
        float alpha = __logf(1.0f + __expf(alpha_primes[f]));
        float beta  = __logf(1.0f + __expf(beta_primes[f])) - alpha;
        float4 c = x0v[f];
#pragma unroll
        for (int i = 0; i < ITEMS; ++i) {
            float dx = x[i].x - c.x;
            float dy = x[i].y - c.y;
            float dz = x[i].z - c.z;
            float dw = x[i].w - c.w;
            float r2 = dx * dx;
            r2 = __builtin_fmaf(dy, dy, r2);
            r2 = __builtin_fmaf(dz, dz, r2);
            r2 = __builtin_fmaf(dw, dw, r2);
            float r = __builtin_amdgcn_sqrtf(r2);            // v_sqrt_f32
            float t = beta * __builtin_amdgcn_rcpf(alpha + r); // v_rcp_f32
            x[i].x = __builtin_fmaf(t, dx, x[i].x);
            x[i].y = __builtin_fmaf(t, dy, x[i].y);
            x[i].z = __builtin_fmaf(t, dz, x[i].z);
            x[i].w = __builtin_fmaf(t, dw, x[i].w);
        }
    }

#pragma unroll
    for (int i = 0; i < ITEMS; ++i) {
        long idx = base + (long)i * BLOCK;
        if (ok[i]) Ov[idx] = x[i];
    }
}

extern "C" void kernel_launch(void* const* d_in, const int* in_sizes, int n_in,
                              void* d_out, int out_size, void* d_ws, size_t ws_size,
                              hipStream_t stream) {
    const float* X   = (const float*)d_in[0];
    const float* x0s = (const float*)d_in[1];
    const float* ap  = (const float*)d_in[2];
    const float* bp  = (const float*)d_in[3];
    float* out = (float*)d_out;

    int batch = in_sizes[0] / DIM; // 8388608
    int blocks = (batch + BLOCK * ITEMS - 1) / (BLOCK * ITEMS);
    radial_flow_kernel<<<blocks, BLOCK, 0, stream>>>(X, x0s, ap, bp, out, batch);
}

// Round 2
// 244.002 us; speedup vs baseline: 1.0224x; 1.0224x over previous
//
#include <hip/hip_runtime.h>

#define N_FLOWS 20
#define DIM 4
#define ITEMS 8
#define BLOCK 256

typedef float v2f __attribute__((ext_vector_type(2)));

// ---------------------------------------------------------------------------
// Setup: one tiny block computes softplus params once, instead of every
// thread of the main kernel doing 20x softplus (80 transcendentals/thread).
// ws layout per flow f (8 floats, 32B): [x0.x, x0.y, x0.z, x0.w, alpha, beta, 0, 0]
// ---------------------------------------------------------------------------
__global__ void radial_setup(const float* __restrict__ x0s,
                             const float* __restrict__ alpha_primes,
                             const float* __restrict__ beta_primes,
                             float* __restrict__ ws) {
    int f = threadIdx.x;
    if (f < N_FLOWS) {
        float alpha = __logf(1.0f + __expf(alpha_primes[f]));
        float beta  = __logf(1.0f + __expf(beta_primes[f])) - alpha;
        float* p = ws + 8 * f;
        p[0] = x0s[4 * f + 0];
        p[1] = x0s[4 * f + 1];
        p[2] = x0s[4 * f + 2];
        p[3] = x0s[4 * f + 3];
        p[4] = alpha;
        p[5] = beta;
        p[6] = 0.0f;
        p[7] = 0.0f;
    }
}

// ---------------------------------------------------------------------------
// Main: 20 chained radial flows. VALU-issue-bound; per flow-item the floor is
// 2 transcendentals (v_sqrt_f32 + v_rcp_f32, ~16 cy/wave64 each). Everything
// else is packed fp32 (v_pk_*) to halve full-rate issue cycles.
// No bounds check: grid covers exact tiles only; tail kernel handles the rest.
// ---------------------------------------------------------------------------
__global__ __launch_bounds__(BLOCK) void radial_main(
    const float4* __restrict__ Xv,
    const float4* __restrict__ P,   // ws as float4: P[2f]=x0, P[2f+1]={alpha,beta,_,_}
    float4* __restrict__ Ov)
{
    const unsigned base = blockIdx.x * (BLOCK * ITEMS) + threadIdx.x;

    v2f a[ITEMS], b[ITEMS];
#pragma unroll
    for (int i = 0; i < ITEMS; ++i) {
        float4 v = Xv[base + i * BLOCK];
        a[i] = (v2f){v.x, v.y};
        b[i] = (v2f){v.z, v.w};
    }

#pragma unroll
    for (int f = 0; f < N_FLOWS; ++f) {
        float4 c  = P[2 * f];       // uniform -> s_load
        float4 ab = P[2 * f + 1];
        v2f c01 = (v2f){c.x, c.y};
        v2f c23 = (v2f){c.z, c.w};
        float alpha = ab.x, beta = ab.y;
#pragma unroll
        for (int i = 0; i < ITEMS; ++i) {
            v2f da = a[i] - c01;          // v_pk_add_f32 (neg)
            v2f db = b[i] - c23;
            v2f q  = da * da;             // v_pk_mul_f32
            q += db * db;                 // v_pk_fma_f32
            float r2 = q.x + q.y;         // v_add_f32
            float r  = __builtin_amdgcn_sqrtf(r2);             // v_sqrt_f32
            float t  = beta * __builtin_amdgcn_rcpf(alpha + r); // v_add + v_rcp + v_mul
            v2f tv = (v2f){t, t};
            a[i] = tv * da + a[i];        // v_pk_fma_f32
            b[i] = tv * db + b[i];
        }
    }

#pragma unroll
    for (int i = 0; i < ITEMS; ++i) {
        float4 v;
        v.x = a[i].x; v.y = a[i].y; v.z = b[i].x; v.w = b[i].y;
        Ov[base + i * BLOCK] = v;
    }
}

// Generic tail: one guarded sample per thread (grid is 0 for BATCH=2^23).
__global__ void radial_tail(const float4* __restrict__ Xv,
                            const float4* __restrict__ P,
                            float4* __restrict__ Ov,
                            int start, int batch)
{
    int idx = start + blockIdx.x * blockDim.x + threadIdx.x;
    if (idx >= batch) return;
    float4 v = Xv[idx];
#pragma unroll
    for (int f = 0; f < N_FLOWS; ++f) {
        float4 c  = P[2 * f];
        float4 ab = P[2 * f + 1];
        float dx = v.x - c.x, dy = v.y - c.y, dz = v.z - c.z, dw = v.w - c.w;
        float r2 = dx * dx + dy * dy + dz * dz + dw * dw;
        float r  = __builtin_amdgcn_sqrtf(r2);
        float t  = ab.y * __builtin_amdgcn_rcpf(ab.x + r);
        v.x += t * dx; v.y += t * dy; v.z += t * dz; v.w += t * dw;
    }
    Ov[idx] = v;
}

extern "C" void kernel_launch(void* const* d_in, const int* in_sizes, int n_in,
                              void* d_out, int out_size, void* d_ws, size_t ws_size,
                              hipStream_t stream) {
    const float* X   = (const float*)d_in[0];
    const float* x0s = (const float*)d_in[1];
    const float* ap  = (const float*)d_in[2];
    const float* bp  = (const float*)d_in[3];
    float* out = (float*)d_out;
    float* ws  = (float*)d_ws;

    int batch = in_sizes[0] / DIM; // 8388608

    radial_setup<<<1, 64, 0, stream>>>(x0s, ap, bp, ws);

    const int tile = BLOCK * ITEMS;
    int full_blocks = batch / tile;
    if (full_blocks > 0)
        radial_main<<<full_blocks, BLOCK, 0, stream>>>(
            (const float4*)X, (const float4*)ws, (float4*)out);

    int done = full_blocks * tile;
    int rem = batch - done;
    if (rem > 0)
        radial_tail<<<(rem + 255) / 256, 256, 0, stream>>>(
            (const float4*)X, (const float4*)ws, (float4*)out, done, batch);
}